// Round 7
// baseline (4950.313 us; speedup 1.0000x reference)
//
#include <hip/hip_runtime.h>
#include <hip/hip_bf16.h>

// ---------------------------------------------------------------------------
// CTM round 6: persistent kernel widened to 512-thread blocks (8 waves/CU,
// 2x memory parallelism) while keeping 256 barrier arrivals. Block = two
// 256-thread halves with private LDS; per-half phases keep the 256-thread
// structure (equal __syncthreads counts per half). Split-K 16 for s1/s2.
// ---------------------------------------------------------------------------

#define B_ 64
#define S_ 512
#define F_ 1024
#define DMODEL 2048
#define DMEM 32
#define DIN 1024
#define NH 16
#define DH 64
#define DOUT 1000
#define NSYNC 512
#define TICKS 16
#define HNLM 32
#define HIST_W 48
#define GPERS 256   // persistent grid size (1 block/CU -> co-resident)
#define NHALF 512   // 2 halves per block

typedef __attribute__((ext_vector_type(8))) short short8;
typedef __attribute__((ext_vector_type(4))) float f32x4;

__device__ inline void store_f(float* p, float v) { *p = v; }
__device__ inline void store_f(__hip_bfloat16* p, float v) { *p = __float2bfloat16(v); }

__device__ inline short f2bs(float f) {
  __hip_bfloat16 h = __float2bfloat16(f);
  return *reinterpret_cast<short*>(&h);
}

__device__ inline float bfs(short x) {
  return __uint_as_float(((unsigned)(unsigned short)x) << 16);
}

__device__ inline float gelu_f(float x) {
  float x3 = x * x * x;
  return 0.5f * x * (1.f + tanhf(0.7978845608028654f * (x + 0.044715f * x3)));
}

__device__ inline float bf_lo(unsigned v) { return __uint_as_float(v << 16); }
__device__ inline float bf_hi(unsigned v) { return __uint_as_float(v & 0xffff0000u); }

// ---------------- software grid barrier ----------------
__device__ __forceinline__ void gbar(int* cnt, int idx) {
  __syncthreads();
  if (threadIdx.x == 0) {
    __hip_atomic_fetch_add(&cnt[idx], 1, __ATOMIC_RELEASE, __HIP_MEMORY_SCOPE_AGENT);
    while (__hip_atomic_load(&cnt[idx], __ATOMIC_RELAXED, __HIP_MEMORY_SCOPE_AGENT) < GPERS) {
      __builtin_amdgcn_s_sleep(16);
    }
    (void)__hip_atomic_load(&cnt[idx], __ATOMIC_ACQUIRE, __HIP_MEMORY_SCOPE_AGENT);
  }
  __syncthreads();
}

// ---------------- weight prep ----------------
__global__ __launch_bounds__(256) void transpose_bf16_kernel(const float* __restrict__ W,
                                                             __hip_bfloat16* __restrict__ Wt,
                                                             int K, int N, int Npad) {
  __shared__ float t[32][33];
  const int tx = threadIdx.x, ty = threadIdx.y;  // 32 x 8
  const int n0 = blockIdx.x * 32, k0 = blockIdx.y * 32;
#pragma unroll
  for (int i = 0; i < 4; i++) {
    int k = k0 + ty + i * 8;
    t[ty + i * 8][tx] = (k < K && n0 + tx < N) ? W[(size_t)k * N + n0 + tx] : 0.f;
  }
  __syncthreads();
#pragma unroll
  for (int i = 0; i < 4; i++) {
    int n = n0 + ty + i * 8;
    if (n < Npad && k0 + tx < K)
      Wt[(size_t)n * K + k0 + tx] = __float2bfloat16(t[tx][ty + i * 8]);
  }
}

__global__ void conv_bf16_kernel(const float* __restrict__ src, __hip_bfloat16* __restrict__ dst,
                                 int n) {
  int i = blockIdx.x * 256 + threadIdx.x;
  if (i < n) dst[i] = __float2bfloat16(src[i]);
}

__global__ void bqaq_kernel(const float* __restrict__ b_q, const float* __restrict__ b_aq,
                            const __hip_bfloat16* __restrict__ Wt_aq, float* __restrict__ b_qaq) {
  int n = blockIdx.x * 256 + threadIdx.x;
  if (n >= DIN) return;
  const __hip_bfloat16* wr = Wt_aq + (size_t)n * DIN;
  float s = b_aq[n];
  for (int k = 0; k < DIN; k++) s += b_q[k] * __bfloat162float(wr[k]);
  b_qaq[n] = s;
}

// ---------------- big MFMA GEMM (precompute) ----------------
// TRANSC: 0 = row-major C[M,N]; 1 = C^T [N,M]; 2 = attention layout
__device__ inline short8 load_chunk(const __hip_bfloat16* p) {
  return *reinterpret_cast<const short8*>(p);
}
__device__ inline short8 load_chunk(const float* p) {
  short8 r;
#pragma unroll
  for (int j = 0; j < 8; j++) r[j] = f2bs(p[j]);
  return r;
}

template <int TRANSC, typename TA, typename TC>
__global__ __launch_bounds__(256) void gemm_big(const TA* __restrict__ A,
                                                const __hip_bfloat16* __restrict__ Bt,
                                                const float* __restrict__ bias,
                                                TC* __restrict__ C, int M, int N, int K) {
  __shared__ short lsA[128 * 64];
  __shared__ short lsB[128 * 64];
  const int tid = threadIdx.x;
  const int l = tid & 63, w = tid >> 6;
  const int wr = (w >> 1) * 64, wc = (w & 1) * 64;
  const int brow = blockIdx.y * 128, bcol = blockIdx.x * 128;
  f32x4 acc[4][4];
#pragma unroll
  for (int i = 0; i < 4; i++)
#pragma unroll
    for (int j = 0; j < 4; j++)
#pragma unroll
      for (int r = 0; r < 4; r++) acc[i][j][r] = 0.f;

  short8 ra[4], rb[4];
  auto gload = [&](int k0) {
#pragma unroll
    for (int q = 0; q < 4; q++) {
      int i = tid + q * 256;
      int row = i >> 3, c = i & 7;
      ra[q] = load_chunk(A + (size_t)(brow + row) * K + k0 + c * 8);
      rb[q] = load_chunk(Bt + (size_t)(bcol + row) * K + k0 + c * 8);
    }
  };
  auto lwrite = [&]() {
#pragma unroll
    for (int q = 0; q < 4; q++) {
      int i = tid + q * 256;
      int row = i >> 3, c = i & 7;
      int sw = c ^ (row & 7);
      *reinterpret_cast<short8*>(&lsA[row * 64 + sw * 8]) = ra[q];
      *reinterpret_cast<short8*>(&lsB[row * 64 + sw * 8]) = rb[q];
    }
  };
  gload(0);
  for (int k0 = 0; k0 < K; k0 += 64) {
    __syncthreads();
    lwrite();
    if (k0 + 64 < K) gload(k0 + 64);
    __syncthreads();
#pragma unroll
    for (int ks = 0; ks < 2; ks++) {
      short8 af[4], bfv[4];
#pragma unroll
      for (int mi = 0; mi < 4; mi++) {
        int row = wr + mi * 16 + (l & 15);
        int c = ks * 4 + (l >> 4);
        af[mi] = *reinterpret_cast<const short8*>(&lsA[row * 64 + (c ^ (row & 7)) * 8]);
      }
#pragma unroll
      for (int ni = 0; ni < 4; ni++) {
        int row = wc + ni * 16 + (l & 15);
        int c = ks * 4 + (l >> 4);
        bfv[ni] = *reinterpret_cast<const short8*>(&lsB[row * 64 + (c ^ (row & 7)) * 8]);
      }
#pragma unroll
      for (int mi = 0; mi < 4; mi++)
#pragma unroll
        for (int ni = 0; ni < 4; ni++)
          acc[mi][ni] =
              __builtin_amdgcn_mfma_f32_16x16x32_bf16(af[mi], bfv[ni], acc[mi][ni], 0, 0, 0);
    }
  }
#pragma unroll
  for (int mi = 0; mi < 4; mi++)
#pragma unroll
    for (int ni = 0; ni < 4; ni++)
#pragma unroll
      for (int r = 0; r < 4; r++) {
        int row = brow + wr + mi * 16 + (l >> 4) * 4 + r;
        int col = bcol + wc + ni * 16 + (l & 15);
        float v = acc[mi][ni][r];
        if (bias) v += bias[col];
        if (TRANSC == 1) {
          store_f(&C[(size_t)col * M + row], v);
        } else if (TRANSC == 2) {
          int bb = row >> 9, s = row & 511, hh = col >> 6, dd = col & 63;
          store_f(&C[(((size_t)(bb * 16 + hh) * 512) + s) * 64 + dd], v);
        } else {
          store_f(&C[(size_t)row * N + col], v);
        }
      }
}

// ---------------- LayerNorm (precompute: kv) ----------------
template <typename TOUT>
__global__ __launch_bounds__(256) void ln_kernel(const float* __restrict__ x,
                                                 const float* __restrict__ g,
                                                 const float* __restrict__ be,
                                                 TOUT* __restrict__ out, int C,
                                                 size_t row_stride, int col_stride) {
  const int row = blockIdx.x;
  const int tid = threadIdx.x;
  const float* xr = x + (size_t)row * C;
  float s = 0.f, s2 = 0.f;
  for (int c = tid; c < C; c += 256) {
    float v = xr[c];
    s += v;
    s2 += v * v;
  }
  __shared__ float r1[256], r2[256];
  r1[tid] = s;
  r2[tid] = s2;
  __syncthreads();
  for (int st = 128; st > 0; st >>= 1) {
    if (tid < st) {
      r1[tid] += r1[tid + st];
      r2[tid] += r2[tid + st];
    }
    __syncthreads();
  }
  float mean = r1[0] / C;
  float var = r2[0] / C - mean * mean;
  float inv = 1.0f / sqrtf(var + 1e-5f);
  for (int c = tid; c < C; c += 256) {
    float v = (xr[c] - mean) * inv * g[c] + be[c];
    store_f(&out[(size_t)row * row_stride + (size_t)c * col_stride], v);
  }
}

// ---------------- init kernels ----------------
__global__ void init_act_kernel(const float* __restrict__ init_state, float* __restrict__ act) {
  int i = blockIdx.x * 256 + threadIdx.x;
  if (i < B_ * DMODEL) act[i] = init_state[i & (DMODEL - 1)];
}

__global__ void init_hist_kernel(const float* __restrict__ init_hist, float* __restrict__ hist) {
  int i = blockIdx.x * 256 + threadIdx.x;
  if (i >= B_ * DMODEL * DMEM) return;
  int m = i & (DMEM - 1);
  int bd = i >> 5;
  int d = bd & (DMODEL - 1);
  hist[(size_t)bd * HIST_W + m] = init_hist[d * DMEM + m];
}

__global__ void init_sync_kernel(const float* __restrict__ init_state,
                                 const float* __restrict__ decay_action,
                                 const float* __restrict__ decay_out,
                                 const int* __restrict__ la, const int* __restrict__ ra,
                                 const int* __restrict__ lo, const int* __restrict__ ro,
                                 float* __restrict__ aA, float* __restrict__ bA,
                                 float* __restrict__ aO, float* __restrict__ bO,
                                 __hip_bfloat16* __restrict__ syncA, float* __restrict__ rAv,
                                 float* __restrict__ rOv) {
  int i = blockIdx.x * 256 + threadIdx.x;
  if (i >= B_ * NSYNC) return;
  int j = i & (NSYNC - 1);
  if (i < NSYNC) {
    rAv[i] = expf(-fminf(fmaxf(decay_action[i], 0.f), 15.f));
    rOv[i] = expf(-fminf(fmaxf(decay_out[i], 0.f), 15.f));
  }
  float pA = init_state[la[j]] * init_state[ra[j]];
  aA[i] = pA;
  bA[i] = 1.f;
  syncA[i] = __float2bfloat16(pA);
  aO[i] = init_state[lo[j]] * init_state[ro[j]];
  bO[i] = 1.f;
}

// ---------------- persistent tick kernel ----------------
struct CArgs {
  const __hip_bfloat16 *Wt_qaq, *Wt_ao, *Wt_s1, *Wt_s2, *Wt_out;
  const __hip_bfloat16 *kh, *vh;  // head-major [b][h][s][d]
  const float *b_qaq, *b_ao, *b_s1, *b_s2, *b_out;
  const float *g_s, *be_s, *g_n, *be_n;
  const float *W_n1, *b_n1, *W_n2, *b_n2;
  const int *la, *ra, *lo, *ro;
  const float *rAv, *rOv;
  float *qhb, *part, *histf, *act, *aA, *bA, *aO, *bO, *nlmraw, *outp;
  __hip_bfloat16 *syncA, *syncO, *attnv, *pre, *h1;
  int* bar;
};

// 64xN-tile MFMA matmul on ONE 256-thread half (htid in [0,256), per-half LDS).
// __syncthreads() is block-wide: both halves of a block must run identical
// iteration counts (guaranteed by task assignment).
template <typename EPI>
__device__ __forceinline__ void mm_tile64(const __hip_bfloat16* __restrict__ A, int lda,
                                          const __hip_bfloat16* __restrict__ Bt, int ldb,
                                          int bcol, int kb, int kchunk, int htid, short* lsA,
                                          short* lsB, EPI epi) {
  const int l = htid & 63, w = htid >> 6;
  f32x4 acc[4];
#pragma unroll
  for (int i = 0; i < 4; i++)
#pragma unroll
    for (int r = 0; r < 4; r++) acc[i][r] = 0.f;
  short8 ra[2], rb[2];
  auto gload = [&](int k0) {
#pragma unroll
    for (int q = 0; q < 2; q++) {
      int i = htid + q * 256;
      int row = i >> 3, c = i & 7;
      ra[q] = *reinterpret_cast<const short8*>(A + (size_t)row * lda + k0 + c * 8);
      rb[q] = *reinterpret_cast<const short8*>(Bt + (size_t)(bcol + row) * ldb + k0 + c * 8);
    }
  };
  auto lwrite = [&]() {
#pragma unroll
    for (int q = 0; q < 2; q++) {
      int i = htid + q * 256;
      int row = i >> 3, c = i & 7;
      int sw = c ^ (row & 7);
      *reinterpret_cast<short8*>(&lsA[row * 64 + sw * 8]) = ra[q];
      *reinterpret_cast<short8*>(&lsB[row * 64 + sw * 8]) = rb[q];
    }
  };
  gload(kb);
  for (int k0 = kb; k0 < kb + kchunk; k0 += 64) {
    __syncthreads();
    lwrite();
    if (k0 + 64 < kb + kchunk) gload(k0 + 64);
    __syncthreads();
#pragma unroll
    for (int ks = 0; ks < 2; ks++) {
      int rowa = w * 16 + (l & 15);
      int c = ks * 4 + (l >> 4);
      short8 af = *reinterpret_cast<const short8*>(&lsA[rowa * 64 + (c ^ (rowa & 7)) * 8]);
#pragma unroll
      for (int ni = 0; ni < 4; ni++) {
        int rowb = ni * 16 + (l & 15);
        short8 bfv = *reinterpret_cast<const short8*>(&lsB[rowb * 64 + (c ^ (rowb & 7)) * 8]);
        acc[ni] = __builtin_amdgcn_mfma_f32_16x16x32_bf16(af, bfv, acc[ni], 0, 0, 0);
      }
    }
  }
#pragma unroll
  for (int ni = 0; ni < 4; ni++)
#pragma unroll
    for (int r = 0; r < 4; r++) {
      int m = w * 16 + (l >> 4) * 4 + r;
      int n = bcol + ni * 16 + (l & 15);
      epi(m, n, acc[ni][r]);
    }
}

__global__ __launch_bounds__(512, 2) void ctm_coop(CArgs a) {
  __shared__ __align__(16) char smem[34816];  // 17408 per half
  const int tid = threadIdx.x;                // 0..511
  const int half = tid >> 8;                  // 0/1
  const int htid = tid & 255;
  const int gbx = blockIdx.x;
  const int hid = gbx * 2 + half;             // half id 0..511
  char* hsm = smem + half * 17408;
  short* lsA = (short*)hsm;
  short* lsB = (short*)(hsm + 8192);
  float* hf = (float*)hsm;   // per-half float view
  float* sf = (float*)smem;  // whole-block float view (8704 floats)
  int bi = 0;

  for (int t = 0; t < TICKS; ++t) {
    // ---- P1: qh GEMM (16 half-tasks) ; pack act -> pre[:,1024:] (rest) ----
    for (int u = hid; u < 16; u += NHALF)
      mm_tile64(a.syncA, NSYNC, a.Wt_qaq, NSYNC, u * 64, 0, NSYNC, htid, lsA, lsB,
                [&](int m, int n, float v) { a.qhb[m * DIN + n] = v + a.b_qaq[n]; });
    if (hid >= 16) {
      int stride = (NHALF - 16) * 256;
      for (int i = (hid - 16) * 256 + htid; i < B_ * DMODEL; i += stride) {
        int b = i >> 11, j = i & (DMODEL - 1);
        a.pre[(size_t)b * 3072 + DIN + j] = __float2bfloat16(a.act[i]);
      }
    }
    gbar(a.bar, bi++);
    // ---- P2: attention (1024 tasks, 2 per half) ----
    for (int u = hid; u < B_ * NH; u += NHALF) {
      const int b = u >> 4, h = u & (NH - 1);
      const __hip_bfloat16* Kp = a.kh + (size_t)u * (S_ * DH);
      const __hip_bfloat16* Vp = a.vh + (size_t)u * (S_ * DH);
      float* qs = hf;           // 64 f
      float* wv = hf + 64;      // 512 f
      float* red = hf + 576;    // 256 f
      float* red2 = hf + 1024;  // 2048 f
      if (htid < DH) qs[htid] = a.qhb[b * DIN + h * DH + htid];
      __syncthreads();
      float sc[2];
#pragma unroll
      for (int r = 0; r < 2; ++r) {
        int s = htid + r * 256;
        const short8* kp = reinterpret_cast<const short8*>(Kp + (size_t)s * DH);
        float accv = 0.f;
#pragma unroll
        for (int q = 0; q < 8; ++q) {
          short8 kk = kp[q];
#pragma unroll
          for (int j = 0; j < 8; ++j) accv += qs[q * 8 + j] * bfs(kk[j]);
        }
        sc[r] = accv * 0.125f;
      }
      red[htid] = fmaxf(sc[0], sc[1]);
      __syncthreads();
      for (int st = 128; st > 0; st >>= 1) {
        if (htid < st) red[htid] = fmaxf(red[htid], red[htid + st]);
        __syncthreads();
      }
      const float mx = red[0];
      __syncthreads();
      float e0 = expf(sc[0] - mx), e1 = expf(sc[1] - mx);
      wv[htid] = e0;
      wv[htid + 256] = e1;
      red[htid] = e0 + e1;
      __syncthreads();
      for (int st = 128; st > 0; st >>= 1) {
        if (htid < st) red[htid] += red[htid + st];
        __syncthreads();
      }
      const float invZ = 1.f / red[0];
      __syncthreads();
      const int d8 = htid & 7, sg = htid >> 3;
      float pacc[8];
#pragma unroll
      for (int j = 0; j < 8; ++j) pacc[j] = 0.f;
      for (int s = sg; s < S_; s += 32) {
        float wgt = wv[s];
        short8 vv = *reinterpret_cast<const short8*>(Vp + (size_t)s * DH + d8 * 8);
#pragma unroll
        for (int j = 0; j < 8; ++j) pacc[j] += wgt * bfs(vv[j]);
      }
#pragma unroll
      for (int j = 0; j < 8; ++j) red2[sg * 64 + d8 * 8 + j] = pacc[j];
      __syncthreads();
      if (htid < DH) {
        float r = 0.f;
#pragma unroll
        for (int g2 = 0; g2 < 32; ++g2) r += red2[g2 * 64 + htid];
        a.attnv[b * DIN + h * DH + htid] = __float2bfloat16(r * invZ);
      }
      __syncthreads();
    }
    gbar(a.bar, bi++);
    // ---- P3: ao GEMM -> pre[:, :1024] (16 half-tasks) ----
    for (int u = hid; u < 16; u += NHALF)
      mm_tile64(a.attnv, DIN, a.Wt_ao, DIN, u * 64, 0, DIN, htid, lsA, lsB,
                [&](int m, int n, float v) {
                  a.pre[(size_t)m * 3072 + n] = __float2bfloat16(v + a.b_ao[n]);
                });
    gbar(a.bar, bi++);
    // ---- P4: s1 GEMM split-K16 (512 half-tasks, chunk 192) ----
    for (int u = hid; u < 512; u += NHALF) {
      int nt = u & 31, ks = u >> 5;
      mm_tile64(a.pre, 3072, a.Wt_s1, 3072, nt * 64, ks * 192, 192, htid, lsA, lsB,
                [&](int m, int n, float v) { a.part[((size_t)ks * 64 + m) * DMODEL + n] = v; });
    }
    gbar(a.bar, bi++);
    // ---- P5: s1 reduce + gelu -> h1 (512 half-tasks) ----
    for (int u = hid; u < 512; u += NHALF) {
      int row = u >> 3, chunk = u & 7;
      int n = chunk * 256 + htid;
      float s = a.b_s1[n];
      for (int ks = 0; ks < 16; ks++) s += a.part[((size_t)ks * 64 + row) * DMODEL + n];
      a.h1[(size_t)row * DMODEL + n] = __float2bfloat16(gelu_f(s));
    }
    gbar(a.bar, bi++);
    // ---- P6: s2 GEMM split-K16 (512 half-tasks, chunk 128) ----
    for (int u = hid; u < 512; u += NHALF) {
      int nt = u & 31, ks = u >> 5;
      mm_tile64(a.h1, DMODEL, a.Wt_s2, DMODEL, nt * 64, ks * 128, 128, htid, lsA, lsB,
                [&](int m, int n, float v) { a.part[((size_t)ks * 64 + m) * DMODEL + n] = v; });
    }
    gbar(a.bar, bi++);
    // ---- P7: s2 reduce + LN -> hist slot 32+t (64 block-tasks, 512 thr) ----
    for (int u = gbx; u < 64; u += GPERS) {
      float v4[4];
      float s = 0.f, s2 = 0.f;
#pragma unroll
      for (int i = 0; i < 4; i++) {
        int n = tid + i * 512;
        float x = a.b_s2[n];
        for (int ks = 0; ks < 16; ks++) x += a.part[((size_t)ks * 64 + u) * DMODEL + n];
        v4[i] = x;
        s += x;
        s2 += x * x;
      }
      float* r1 = sf;
      float* r2 = sf + 512;
      r1[tid] = s;
      r2[tid] = s2;
      __syncthreads();
      for (int st = 256; st > 0; st >>= 1) {
        if (tid < st) {
          r1[tid] += r1[tid + st];
          r2[tid] += r2[tid + st];
        }
        __syncthreads();
      }
      float mean = r1[0] / DMODEL;
      float var = r2[0] / DMODEL - mean * mean;
      float inv = 1.f / sqrtf(var + 1e-5f);
      __syncthreads();
#pragma unroll
      for (int i = 0; i < 4; i++) {
        int n = tid + i * 512;
        float pa = (v4[i] - mean) * inv * a.g_s[n] + a.be_s[n];
        a.histf[((size_t)u * DMODEL + n) * HIST_W + 32 + t] = pa;
      }
      __syncthreads();
    }
    gbar(a.bar, bi++);
    // ---- P8: NLM (512 half-tasks) ----
    for (int u = hid; u < 512; u += NHALF) {
      float* w1s = hf;         // 4096 f
      float* b1s = hf + 4096;  // 128 f
      int d0 = u * 4;
      for (int i = htid; i < 4096; i += 256) w1s[i] = a.W_n1[(size_t)d0 * 1024 + i];
      if (htid < 128) b1s[htid] = a.b_n1[d0 * 32 + htid];
      __syncthreads();
      int b = htid & 63, dsub = htid >> 6;
      int d = d0 + dsub;
      const float* hw = a.histf + ((size_t)(b * DMODEL + d)) * HIST_W + t + 1;
      float win[DMEM];
#pragma unroll
      for (int m = 0; m < DMEM; ++m) win[m] = hw[m];
      const float* w1 = w1s + dsub * 1024;
      const float* bb = b1s + dsub * 32;
      const float* w2 = a.W_n2 + d * HNLM;
      float acc = 0.f;
      for (int h = 0; h < HNLM; ++h) {
        float s = bb[h];
#pragma unroll
        for (int m = 0; m < DMEM; ++m) s += win[m] * w1[m * HNLM + h];
        acc += fmaxf(s, 0.f) * w2[h];
      }
      a.nlmraw[(size_t)b * DMODEL + d] = acc + a.b_n2[d];
      __syncthreads();
    }
    gbar(a.bar, bi++);
    // ---- P9: LN(nlmraw)->act ; syncA(t+1), syncO(t) (64 block-tasks) ----
    for (int u = gbx; u < 64; u += GPERS) {
      const float* xr = a.nlmraw + (size_t)u * DMODEL;
      float* arow = sf;        // 2048 f
      float* r1 = sf + 2048;   // 512 f
      float* r2 = sf + 2560;   // 512 f
      float xv[4];
      float s = 0.f, s2 = 0.f;
#pragma unroll
      for (int i = 0; i < 4; i++) {
        float x = xr[tid + i * 512];
        xv[i] = x;
        s += x;
        s2 += x * x;
      }
      r1[tid] = s;
      r2[tid] = s2;
      __syncthreads();
      for (int st = 256; st > 0; st >>= 1) {
        if (tid < st) {
          r1[tid] += r1[tid + st];
          r2[tid] += r2[tid + st];
        }
        __syncthreads();
      }
      float mean = r1[0] / DMODEL;
      float var = r2[0] / DMODEL - mean * mean;
      float inv = 1.f / sqrtf(var + 1e-5f);
      __syncthreads();
#pragma unroll
      for (int i = 0; i < 4; i++) {
        int n = tid + i * 512;
        float av = (xv[i] - mean) * inv * a.g_n[n] + a.be_n[n];
        a.act[(size_t)u * DMODEL + n] = av;
        arow[n] = av;
      }
      __syncthreads();
      for (int j = tid; j < NSYNC; j += 512) {
        size_t idx = (size_t)u * NSYNC + j;
        float pA = arow[a.la[j]] * arow[a.ra[j]];
        float r = a.rAv[j];
        float av2 = r * a.aA[idx] + pA, bv2 = r * a.bA[idx] + 1.f;
        a.aA[idx] = av2;
        a.bA[idx] = bv2;
        a.syncA[idx] = __float2bfloat16(av2 / sqrtf(bv2));
        float pO = arow[a.lo[j]] * arow[a.ro[j]];
        float ro = a.rOv[j];
        av2 = ro * a.aO[idx] + pO;
        bv2 = ro * a.bO[idx] + 1.f;
        a.aO[idx] = av2;
        a.bO[idx] = bv2;
        a.syncO[idx] = __float2bfloat16(av2 / sqrtf(bv2));
      }
      __syncthreads();
    }
    // (no barrier: P10 task u consumed syncO row u written by the SAME block)
    // ---- P10: output head (64 block-tasks, 512 thr) ----
    for (int u = gbx; u < 64; u += GPERS) {
      float* so = sf;          // 512 f
      float* pv = sf + 512;    // 1024 f
      float* red = sf + 1536;  // 512 f
      so[tid] = __bfloat162float(a.syncO[(size_t)u * NSYNC + tid]);
      __syncthreads();
      float pr[2];
#pragma unroll
      for (int i = 0; i < 2; i++) {
        int n = tid + i * 512;
        pr[i] = 0.f;
        if (n < DOUT) {
          const unsigned* wr = reinterpret_cast<const unsigned*>(a.Wt_out + (size_t)n * NSYNC);
          float sacc = a.b_out[n];
          for (int c = 0; c < 256; c++) {
            unsigned uu = wr[c];
            sacc += so[2 * c] * bf_lo(uu) + so[2 * c + 1] * bf_hi(uu);
          }
          pr[i] = sacc;
          pv[n] = sacc;
        }
      }
      __syncthreads();
      float m = -1e30f;
      for (int o = tid; o < DOUT; o += 512) m = fmaxf(m, pv[o]);
      red[tid] = m;
      __syncthreads();
      for (int st = 256; st > 0; st >>= 1) {
        if (tid < st) red[tid] = fmaxf(red[tid], red[tid + st]);
        __syncthreads();
      }
      m = red[0];
      __syncthreads();
      float z = 0.f, s1 = 0.f;
      for (int o = tid; o < DOUT; o += 512) {
        float wv2 = pv[o] - m;
        float e = expf(wv2);
        z += e;
        s1 += e * wv2;
      }
      red[tid] = z;
      __syncthreads();
      for (int st = 256; st > 0; st >>= 1) {
        if (tid < st) red[tid] += red[tid + st];
        __syncthreads();
      }
      const float Z = red[0];
      __syncthreads();
      red[tid] = s1;
      __syncthreads();
      for (int st = 256; st > 0; st >>= 1) {
        if (tid < st) red[tid] += red[tid + st];
        __syncthreads();
      }
      const float S1 = red[0];
      const float ne = -(S1 / Z - logf(Z)) / 6.907755278982137f;
#pragma unroll
      for (int i = 0; i < 2; i++) {
        int n = tid + i * 512;
        if (n < DOUT) a.outp[((size_t)u * DOUT + n) * TICKS + t] = pr[i];
      }
      if (tid == 0) {
        float* c = a.outp + (size_t)B_ * DOUT * TICKS;
        c[u * 2 * TICKS + t] = ne;
        c[u * 2 * TICKS + TICKS + t] = 1.f - ne;
      }
      __syncthreads();
    }
    gbar(a.bar, bi++);
  }
}

// ---------------------------------------------------------------------------
extern "C" void kernel_launch(void* const* d_in, const int* in_sizes, int n_in,
                              void* d_out, int out_size, void* d_ws, size_t ws_size,
                              hipStream_t stream) {
  const float* x = (const float*)d_in[0];
  const float* W_kv = (const float*)d_in[1];
  const float* b_kv = (const float*)d_in[2];
  const float* g_kv = (const float*)d_in[3];
  const float* be_kv = (const float*)d_in[4];
  const float* W_q = (const float*)d_in[5];
  const float* b_q = (const float*)d_in[6];
  const float* W_aq = (const float*)d_in[7];
  const float* b_aq = (const float*)d_in[8];
  const float* W_ak = (const float*)d_in[9];
  const float* b_ak = (const float*)d_in[10];
  const float* W_av = (const float*)d_in[11];
  const float* b_av = (const float*)d_in[12];
  const float* W_ao = (const float*)d_in[13];
  const float* b_ao = (const float*)d_in[14];
  const float* W_s1 = (const float*)d_in[15];
  const float* b_s1 = (const float*)d_in[16];
  const float* W_s2 = (const float*)d_in[17];
  const float* b_s2 = (const float*)d_in[18];
  const float* g_s = (const float*)d_in[19];
  const float* be_s = (const float*)d_in[20];
  const float* W_n1 = (const float*)d_in[21];
  const float* b_n1 = (const float*)d_in[22];
  const float* W_n2 = (const float*)d_in[23];
  const float* b_n2 = (const float*)d_in[24];
  const float* g_n = (const float*)d_in[25];
  const float* be_n = (const float*)d_in[26];
  const float* init_state = (const float*)d_in[27];
  const float* init_hist = (const float*)d_in[28];
  const float* decay_action = (const float*)d_in[29];
  const float* decay_out = (const float*)d_in[30];
  const float* W_out = (const float*)d_in[31];
  const float* b_out = (const float*)d_in[32];
  const int* idx_la = (const int*)d_in[33];
  const int* idx_ra = (const int*)d_in[34];
  const int* idx_lo = (const int*)d_in[35];
  const int* idx_ro = (const int*)d_in[36];
  float* out = (float*)d_out;

  // ---- workspace carve ----
  char* wsb = (char*)d_ws;
  size_t off = 0;
  auto alloc = [&](size_t bytes) -> char* {
    char* p = wsb + off;
    off += (bytes + 255) & ~(size_t)255;
    return p;
  };
  const size_t MS = (size_t)B_ * S_;  // 32768
  char* regionA = alloc(MS * DIN * 4);  // kvraw fp32; later kh+vh bf16 (head-major)
  __hip_bfloat16* kv = (__hip_bfloat16*)alloc(MS * DIN * 2);
  float* histf = (float*)alloc((size_t)B_ * DMODEL * HIST_W * 4);
  __hip_bfloat16* Wt_kv = (__hip_bfloat16*)alloc((size_t)DIN * F_ * 2);
  __hip_bfloat16* Wt_ak = (__hip_bfloat16*)alloc((size_t)DIN * DIN * 2);
  __hip_bfloat16* Wt_av = (__hip_bfloat16*)alloc((size_t)DIN * DIN * 2);
  __hip_bfloat16* Wt_aq = (__hip_bfloat16*)alloc((size_t)DIN * DIN * 2);
  __hip_bfloat16* Wt_ao = (__hip_bfloat16*)alloc((size_t)DIN * DIN * 2);
  __hip_bfloat16* W_qb = (__hip_bfloat16*)alloc((size_t)NSYNC * DIN * 2);
  __hip_bfloat16* Wt_qaq = (__hip_bfloat16*)alloc((size_t)DIN * NSYNC * 2);
  __hip_bfloat16* Wt_s1 = (__hip_bfloat16*)alloc((size_t)DMODEL * (DIN + DMODEL) * 2);
  __hip_bfloat16* Wt_s2 = (__hip_bfloat16*)alloc((size_t)DMODEL * DMODEL * 2);
  __hip_bfloat16* Wt_out = (__hip_bfloat16*)alloc((size_t)DOUT * NSYNC * 2);
  float* b_qaq = (float*)alloc(DIN * 4);
  float* partial = (float*)alloc((size_t)16 * 64 * DMODEL * 4);  // split-K 16
  float* act = (float*)alloc((size_t)B_ * DMODEL * 4);
  float* aA = (float*)alloc((size_t)B_ * NSYNC * 4);
  float* bA = (float*)alloc((size_t)B_ * NSYNC * 4);
  float* aO = (float*)alloc((size_t)B_ * NSYNC * 4);
  float* bO = (float*)alloc((size_t)B_ * NSYNC * 4);
  __hip_bfloat16* syncA = (__hip_bfloat16*)alloc((size_t)B_ * NSYNC * 2);
  __hip_bfloat16* syncO = (__hip_bfloat16*)alloc((size_t)B_ * NSYNC * 2);
  float* qhb = (float*)alloc((size_t)B_ * DIN * 4);
  __hip_bfloat16* attnv = (__hip_bfloat16*)alloc((size_t)B_ * DIN * 2);
  __hip_bfloat16* pre = (__hip_bfloat16*)alloc((size_t)B_ * (DIN + DMODEL) * 2);
  __hip_bfloat16* h1 = (__hip_bfloat16*)alloc((size_t)B_ * DMODEL * 2);
  float* nlmraw = (float*)alloc((size_t)B_ * DMODEL * 4);
  float* rAv = (float*)alloc(NSYNC * 4);
  float* rOv = (float*)alloc(NSYNC * 4);
  int* gbarrier = (int*)alloc(1024);  // 256 barrier slots (144 used)

  float* kvraw = (float*)regionA;
  __hip_bfloat16* kh = (__hip_bfloat16*)regionA;                   // [b][h][s][d]
  __hip_bfloat16* vh = (__hip_bfloat16*)(regionA + MS * DIN * 2);  // [b][h][s][d]

  hipMemsetAsync(gbarrier, 0, 1024, stream);

  dim3 t32x8(32, 8);
  // ---- weight prep ----
  transpose_bf16_kernel<<<dim3(F_ / 32, DIN / 32), t32x8, 0, stream>>>(W_kv, Wt_kv, F_, DIN, DIN);
  transpose_bf16_kernel<<<dim3(DIN / 32, DIN / 32), t32x8, 0, stream>>>(W_ak, Wt_ak, DIN, DIN, DIN);
  transpose_bf16_kernel<<<dim3(DIN / 32, DIN / 32), t32x8, 0, stream>>>(W_av, Wt_av, DIN, DIN, DIN);
  transpose_bf16_kernel<<<dim3(DIN / 32, DIN / 32), t32x8, 0, stream>>>(W_aq, Wt_aq, DIN, DIN, DIN);
  transpose_bf16_kernel<<<dim3(DIN / 32, DIN / 32), t32x8, 0, stream>>>(W_ao, Wt_ao, DIN, DIN, DIN);
  transpose_bf16_kernel<<<dim3(DMODEL / 32, (DIN + DMODEL) / 32), t32x8, 0, stream>>>(
      W_s1, Wt_s1, DIN + DMODEL, DMODEL, DMODEL);
  transpose_bf16_kernel<<<dim3(DMODEL / 32, DMODEL / 32), t32x8, 0, stream>>>(W_s2, Wt_s2, DMODEL,
                                                                              DMODEL, DMODEL);
  transpose_bf16_kernel<<<dim3((DOUT + 31) / 32, NSYNC / 32), t32x8, 0, stream>>>(
      W_out, Wt_out, NSYNC, DOUT, DOUT);
  conv_bf16_kernel<<<(NSYNC * DIN + 255) / 256, 256, 0, stream>>>(W_q, W_qb, NSYNC * DIN);
  bqaq_kernel<<<4, 256, 0, stream>>>(b_q, b_aq, Wt_aq, b_qaq);

  // ---- precompute ----
  gemm_big<0, float, float><<<dim3(DIN / 128, MS / 128), 256, 0, stream>>>(x, Wt_kv, b_kv, kvraw,
                                                                           (int)MS, DIN, F_);
  ln_kernel<__hip_bfloat16><<<(int)MS, 256, 0, stream>>>(kvraw, g_kv, be_kv, kv, DIN, DIN, 1);
  gemm_big<2, __hip_bfloat16, __hip_bfloat16><<<dim3(DIN / 128, MS / 128), 256, 0, stream>>>(
      kv, Wt_ak, b_ak, kh, (int)MS, DIN, DIN);
  gemm_big<2, __hip_bfloat16, __hip_bfloat16><<<dim3(DIN / 128, MS / 128), 256, 0, stream>>>(
      kv, Wt_av, b_av, vh, (int)MS, DIN, DIN);
  gemm_big<1, __hip_bfloat16, __hip_bfloat16><<<dim3(DIN / 128, NSYNC / 128), 256, 0, stream>>>(
      W_qb, Wt_aq, nullptr, Wt_qaq, NSYNC, DIN, DIN);

  // ---- state init ----
  init_act_kernel<<<(B_ * DMODEL + 255) / 256, 256, 0, stream>>>(init_state, act);
  init_hist_kernel<<<(B_ * DMODEL * DMEM + 255) / 256, 256, 0, stream>>>(init_hist, histf);
  init_sync_kernel<<<(B_ * NSYNC + 255) / 256, 256, 0, stream>>>(
      init_state, decay_action, decay_out, idx_la, idx_ra, idx_lo, idx_ro, aA, bA, aO, bO, syncA,
      rAv, rOv);

  // ---- persistent tick loop (256 blocks x 512 threads, 1 block/CU) ----
  CArgs ca;
  ca.Wt_qaq = Wt_qaq; ca.Wt_ao = Wt_ao; ca.Wt_s1 = Wt_s1; ca.Wt_s2 = Wt_s2; ca.Wt_out = Wt_out;
  ca.kh = kh; ca.vh = vh;
  ca.b_qaq = b_qaq; ca.b_ao = b_ao; ca.b_s1 = b_s1; ca.b_s2 = b_s2; ca.b_out = b_out;
  ca.g_s = g_s; ca.be_s = be_s; ca.g_n = g_n; ca.be_n = be_n;
  ca.W_n1 = W_n1; ca.b_n1 = b_n1; ca.W_n2 = W_n2; ca.b_n2 = b_n2;
  ca.la = idx_la; ca.ra = idx_ra; ca.lo = idx_lo; ca.ro = idx_ro;
  ca.rAv = rAv; ca.rOv = rOv;
  ca.qhb = qhb; ca.part = partial; ca.histf = histf; ca.act = act;
  ca.aA = aA; ca.bA = bA; ca.aO = aO; ca.bO = bO;
  ca.nlmraw = nlmraw; ca.outp = out;
  ca.syncA = syncA; ca.syncO = syncO; ca.attnv = attnv; ca.pre = pre; ca.h1 = h1;
  ca.bar = gbarrier;

  ctm_coop<<<GPERS, 512, 0, stream>>>(ca);

  (void)in_sizes; (void)n_in; (void)out_size; (void)ws_size;
}

// Round 8
// 4341.536 us; speedup vs baseline: 1.1402x; 1.1402x over previous
//
#include <hip/hip_runtime.h>
#include <hip/hip_bf16.h>

// ---------------------------------------------------------------------------
// CTM round 7: two-level tree grid barrier.
// Round-6 post-mortem: doubling waves/CU changed nothing -> not latency-bound;
// ~3.5ms unexplained = 144 barriers x ~25us of same-line RMW+poll contention
// (256 RMWs serialize on one 4B counter; 256 pollers queue on the hot line).
// Now: 16 group counters on separate 128B lines (16 arrivals each, ACQ_REL),
// group-last promotes to root (16 RMWs), waiters poll root (written 16x only)
// then one ACQUIRE. Release-sequence transitivity preserves cross-XCD
// visibility without any block->XCD mapping assumption.
// ---------------------------------------------------------------------------

#define B_ 64
#define S_ 512
#define F_ 1024
#define DMODEL 2048
#define DMEM 32
#define DIN 1024
#define NH 16
#define DH 64
#define DOUT 1000
#define NSYNC 512
#define TICKS 16
#define HNLM 32
#define HIST_W 48
#define GPERS 256   // persistent grid size
#define NHALF 512   // 2 halves per block
#define NGRP 16     // barrier groups
#define GSZ (GPERS / NGRP)          // arrivals per group = 16
#define BAR_STRIDE 2176             // (NGRP+1) lines * 128B per barrier slot
#define BAR_SLOTS 160

typedef __attribute__((ext_vector_type(8))) short short8;
typedef __attribute__((ext_vector_type(4))) float f32x4;

__device__ inline void store_f(float* p, float v) { *p = v; }
__device__ inline void store_f(__hip_bfloat16* p, float v) { *p = __float2bfloat16(v); }

__device__ inline short f2bs(float f) {
  __hip_bfloat16 h = __float2bfloat16(f);
  return *reinterpret_cast<short*>(&h);
}

__device__ inline float bfs(short x) {
  return __uint_as_float(((unsigned)(unsigned short)x) << 16);
}

__device__ inline float gelu_f(float x) {
  float x3 = x * x * x;
  return 0.5f * x * (1.f + tanhf(0.7978845608028654f * (x + 0.044715f * x3)));
}

__device__ inline float bf_lo(unsigned v) { return __uint_as_float(v << 16); }
__device__ inline float bf_hi(unsigned v) { return __uint_as_float(v & 0xffff0000u); }

// ---------------- two-level software grid barrier ----------------
__device__ __forceinline__ void gbar(char* bar, int idx) {
  __syncthreads();
  if (threadIdx.x == 0) {
    char* base = bar + (size_t)idx * BAR_STRIDE;
    int g = blockIdx.x & (NGRP - 1);
    int* gc = (int*)(base + g * 128);
    int* root = (int*)(base + NGRP * 128);
    // arrival: ACQ_REL RMW on group line (16 contenders per line)
    int pg = __hip_atomic_fetch_add(gc, 1, __ATOMIC_ACQ_REL, __HIP_MEMORY_SCOPE_AGENT);
    if (pg == GSZ - 1) {
      // group-last: promote to root (16 RMWs total on root line)
      __hip_atomic_fetch_add(root, 1, __ATOMIC_ACQ_REL, __HIP_MEMORY_SCOPE_AGENT);
    }
    // wait: relaxed poll of root (only 16 writes land on this line)
    while (__hip_atomic_load(root, __ATOMIC_RELAXED, __HIP_MEMORY_SCOPE_AGENT) < NGRP) {
      __builtin_amdgcn_s_sleep(8);
    }
    (void)__hip_atomic_load(root, __ATOMIC_ACQUIRE, __HIP_MEMORY_SCOPE_AGENT);
  }
  __syncthreads();
}

// ---------------- weight prep ----------------
__global__ __launch_bounds__(256) void transpose_bf16_kernel(const float* __restrict__ W,
                                                             __hip_bfloat16* __restrict__ Wt,
                                                             int K, int N, int Npad) {
  __shared__ float t[32][33];
  const int tx = threadIdx.x, ty = threadIdx.y;  // 32 x 8
  const int n0 = blockIdx.x * 32, k0 = blockIdx.y * 32;
#pragma unroll
  for (int i = 0; i < 4; i++) {
    int k = k0 + ty + i * 8;
    t[ty + i * 8][tx] = (k < K && n0 + tx < N) ? W[(size_t)k * N + n0 + tx] : 0.f;
  }
  __syncthreads();
#pragma unroll
  for (int i = 0; i < 4; i++) {
    int n = n0 + ty + i * 8;
    if (n < Npad && k0 + tx < K)
      Wt[(size_t)n * K + k0 + tx] = __float2bfloat16(t[tx][ty + i * 8]);
  }
}

__global__ void conv_bf16_kernel(const float* __restrict__ src, __hip_bfloat16* __restrict__ dst,
                                 int n) {
  int i = blockIdx.x * 256 + threadIdx.x;
  if (i < n) dst[i] = __float2bfloat16(src[i]);
}

__global__ void bqaq_kernel(const float* __restrict__ b_q, const float* __restrict__ b_aq,
                            const __hip_bfloat16* __restrict__ Wt_aq, float* __restrict__ b_qaq) {
  int n = blockIdx.x * 256 + threadIdx.x;
  if (n >= DIN) return;
  const __hip_bfloat16* wr = Wt_aq + (size_t)n * DIN;
  float s = b_aq[n];
  for (int k = 0; k < DIN; k++) s += b_q[k] * __bfloat162float(wr[k]);
  b_qaq[n] = s;
}

// ---------------- big MFMA GEMM (precompute) ----------------
// TRANSC: 0 = row-major C[M,N]; 1 = C^T [N,M]; 2 = attention layout
__device__ inline short8 load_chunk(const __hip_bfloat16* p) {
  return *reinterpret_cast<const short8*>(p);
}
__device__ inline short8 load_chunk(const float* p) {
  short8 r;
#pragma unroll
  for (int j = 0; j < 8; j++) r[j] = f2bs(p[j]);
  return r;
}

template <int TRANSC, typename TA, typename TC>
__global__ __launch_bounds__(256) void gemm_big(const TA* __restrict__ A,
                                                const __hip_bfloat16* __restrict__ Bt,
                                                const float* __restrict__ bias,
                                                TC* __restrict__ C, int M, int N, int K) {
  __shared__ short lsA[128 * 64];
  __shared__ short lsB[128 * 64];
  const int tid = threadIdx.x;
  const int l = tid & 63, w = tid >> 6;
  const int wr = (w >> 1) * 64, wc = (w & 1) * 64;
  const int brow = blockIdx.y * 128, bcol = blockIdx.x * 128;
  f32x4 acc[4][4];
#pragma unroll
  for (int i = 0; i < 4; i++)
#pragma unroll
    for (int j = 0; j < 4; j++)
#pragma unroll
      for (int r = 0; r < 4; r++) acc[i][j][r] = 0.f;

  short8 ra[4], rb[4];
  auto gload = [&](int k0) {
#pragma unroll
    for (int q = 0; q < 4; q++) {
      int i = tid + q * 256;
      int row = i >> 3, c = i & 7;
      ra[q] = load_chunk(A + (size_t)(brow + row) * K + k0 + c * 8);
      rb[q] = load_chunk(Bt + (size_t)(bcol + row) * K + k0 + c * 8);
    }
  };
  auto lwrite = [&]() {
#pragma unroll
    for (int q = 0; q < 4; q++) {
      int i = tid + q * 256;
      int row = i >> 3, c = i & 7;
      int sw = c ^ (row & 7);
      *reinterpret_cast<short8*>(&lsA[row * 64 + sw * 8]) = ra[q];
      *reinterpret_cast<short8*>(&lsB[row * 64 + sw * 8]) = rb[q];
    }
  };
  gload(0);
  for (int k0 = 0; k0 < K; k0 += 64) {
    __syncthreads();
    lwrite();
    if (k0 + 64 < K) gload(k0 + 64);
    __syncthreads();
#pragma unroll
    for (int ks = 0; ks < 2; ks++) {
      short8 af[4], bfv[4];
#pragma unroll
      for (int mi = 0; mi < 4; mi++) {
        int row = wr + mi * 16 + (l & 15);
        int c = ks * 4 + (l >> 4);
        af[mi] = *reinterpret_cast<const short8*>(&lsA[row * 64 + (c ^ (row & 7)) * 8]);
      }
#pragma unroll
      for (int ni = 0; ni < 4; ni++) {
        int row = wc + ni * 16 + (l & 15);
        int c = ks * 4 + (l >> 4);
        bfv[ni] = *reinterpret_cast<const short8*>(&lsB[row * 64 + (c ^ (row & 7)) * 8]);
      }
#pragma unroll
      for (int mi = 0; mi < 4; mi++)
#pragma unroll
        for (int ni = 0; ni < 4; ni++)
          acc[mi][ni] =
              __builtin_amdgcn_mfma_f32_16x16x32_bf16(af[mi], bfv[ni], acc[mi][ni], 0, 0, 0);
    }
  }
#pragma unroll
  for (int mi = 0; mi < 4; mi++)
#pragma unroll
    for (int ni = 0; ni < 4; ni++)
#pragma unroll
      for (int r = 0; r < 4; r++) {
        int row = brow + wr + mi * 16 + (l >> 4) * 4 + r;
        int col = bcol + wc + ni * 16 + (l & 15);
        float v = acc[mi][ni][r];
        if (bias) v += bias[col];
        if (TRANSC == 1) {
          store_f(&C[(size_t)col * M + row], v);
        } else if (TRANSC == 2) {
          int bb = row >> 9, s = row & 511, hh = col >> 6, dd = col & 63;
          store_f(&C[(((size_t)(bb * 16 + hh) * 512) + s) * 64 + dd], v);
        } else {
          store_f(&C[(size_t)row * N + col], v);
        }
      }
}

// ---------------- LayerNorm (precompute: kv) ----------------
template <typename TOUT>
__global__ __launch_bounds__(256) void ln_kernel(const float* __restrict__ x,
                                                 const float* __restrict__ g,
                                                 const float* __restrict__ be,
                                                 TOUT* __restrict__ out, int C,
                                                 size_t row_stride, int col_stride) {
  const int row = blockIdx.x;
  const int tid = threadIdx.x;
  const float* xr = x + (size_t)row * C;
  float s = 0.f, s2 = 0.f;
  for (int c = tid; c < C; c += 256) {
    float v = xr[c];
    s += v;
    s2 += v * v;
  }
  __shared__ float r1[256], r2[256];
  r1[tid] = s;
  r2[tid] = s2;
  __syncthreads();
  for (int st = 128; st > 0; st >>= 1) {
    if (tid < st) {
      r1[tid] += r1[tid + st];
      r2[tid] += r2[tid + st];
    }
    __syncthreads();
  }
  float mean = r1[0] / C;
  float var = r2[0] / C - mean * mean;
  float inv = 1.0f / sqrtf(var + 1e-5f);
  for (int c = tid; c < C; c += 256) {
    float v = (xr[c] - mean) * inv * g[c] + be[c];
    store_f(&out[(size_t)row * row_stride + (size_t)c * col_stride], v);
  }
}

// ---------------- init kernels ----------------
__global__ void init_act_kernel(const float* __restrict__ init_state, float* __restrict__ act) {
  int i = blockIdx.x * 256 + threadIdx.x;
  if (i < B_ * DMODEL) act[i] = init_state[i & (DMODEL - 1)];
}

__global__ void init_hist_kernel(const float* __restrict__ init_hist, float* __restrict__ hist) {
  int i = blockIdx.x * 256 + threadIdx.x;
  if (i >= B_ * DMODEL * DMEM) return;
  int m = i & (DMEM - 1);
  int bd = i >> 5;
  int d = bd & (DMODEL - 1);
  hist[(size_t)bd * HIST_W + m] = init_hist[d * DMEM + m];
}

__global__ void init_sync_kernel(const float* __restrict__ init_state,
                                 const float* __restrict__ decay_action,
                                 const float* __restrict__ decay_out,
                                 const int* __restrict__ la, const int* __restrict__ ra,
                                 const int* __restrict__ lo, const int* __restrict__ ro,
                                 float* __restrict__ aA, float* __restrict__ bA,
                                 float* __restrict__ aO, float* __restrict__ bO,
                                 __hip_bfloat16* __restrict__ syncA, float* __restrict__ rAv,
                                 float* __restrict__ rOv) {
  int i = blockIdx.x * 256 + threadIdx.x;
  if (i >= B_ * NSYNC) return;
  int j = i & (NSYNC - 1);
  if (i < NSYNC) {
    rAv[i] = expf(-fminf(fmaxf(decay_action[i], 0.f), 15.f));
    rOv[i] = expf(-fminf(fmaxf(decay_out[i], 0.f), 15.f));
  }
  float pA = init_state[la[j]] * init_state[ra[j]];
  aA[i] = pA;
  bA[i] = 1.f;
  syncA[i] = __float2bfloat16(pA);
  aO[i] = init_state[lo[j]] * init_state[ro[j]];
  bO[i] = 1.f;
}

// ---------------- persistent tick kernel ----------------
struct CArgs {
  const __hip_bfloat16 *Wt_qaq, *Wt_ao, *Wt_s1, *Wt_s2, *Wt_out;
  const __hip_bfloat16 *kh, *vh;  // head-major [b][h][s][d]
  const float *b_qaq, *b_ao, *b_s1, *b_s2, *b_out;
  const float *g_s, *be_s, *g_n, *be_n;
  const float *W_n1, *b_n1, *W_n2, *b_n2;
  const int *la, *ra, *lo, *ro;
  const float *rAv, *rOv;
  float *qhb, *part, *histf, *act, *aA, *bA, *aO, *bO, *nlmraw, *outp;
  __hip_bfloat16 *syncA, *syncO, *attnv, *pre, *h1;
  char* bar;
};

// 64xN-tile MFMA matmul on ONE 256-thread half (htid in [0,256), per-half LDS).
template <typename EPI>
__device__ __forceinline__ void mm_tile64(const __hip_bfloat16* __restrict__ A, int lda,
                                          const __hip_bfloat16* __restrict__ Bt, int ldb,
                                          int bcol, int kb, int kchunk, int htid, short* lsA,
                                          short* lsB, EPI epi) {
  const int l = htid & 63, w = htid >> 6;
  f32x4 acc[4];
#pragma unroll
  for (int i = 0; i < 4; i++)
#pragma unroll
    for (int r = 0; r < 4; r++) acc[i][r] = 0.f;
  short8 ra[2], rb[2];
  auto gload = [&](int k0) {
#pragma unroll
    for (int q = 0; q < 2; q++) {
      int i = htid + q * 256;
      int row = i >> 3, c = i & 7;
      ra[q] = *reinterpret_cast<const short8*>(A + (size_t)row * lda + k0 + c * 8);
      rb[q] = *reinterpret_cast<const short8*>(Bt + (size_t)(bcol + row) * ldb + k0 + c * 8);
    }
  };
  auto lwrite = [&]() {
#pragma unroll
    for (int q = 0; q < 2; q++) {
      int i = htid + q * 256;
      int row = i >> 3, c = i & 7;
      int sw = c ^ (row & 7);
      *reinterpret_cast<short8*>(&lsA[row * 64 + sw * 8]) = ra[q];
      *reinterpret_cast<short8*>(&lsB[row * 64 + sw * 8]) = rb[q];
    }
  };
  gload(kb);
  for (int k0 = kb; k0 < kb + kchunk; k0 += 64) {
    __syncthreads();
    lwrite();
    if (k0 + 64 < kb + kchunk) gload(k0 + 64);
    __syncthreads();
#pragma unroll
    for (int ks = 0; ks < 2; ks++) {
      int rowa = w * 16 + (l & 15);
      int c = ks * 4 + (l >> 4);
      short8 af = *reinterpret_cast<const short8*>(&lsA[rowa * 64 + (c ^ (rowa & 7)) * 8]);
#pragma unroll
      for (int ni = 0; ni < 4; ni++) {
        int rowb = ni * 16 + (l & 15);
        short8 bfv = *reinterpret_cast<const short8*>(&lsB[rowb * 64 + (c ^ (rowb & 7)) * 8]);
        acc[ni] = __builtin_amdgcn_mfma_f32_16x16x32_bf16(af, bfv, acc[ni], 0, 0, 0);
      }
    }
  }
#pragma unroll
  for (int ni = 0; ni < 4; ni++)
#pragma unroll
    for (int r = 0; r < 4; r++) {
      int m = w * 16 + (l >> 4) * 4 + r;
      int n = bcol + ni * 16 + (l & 15);
      epi(m, n, acc[ni][r]);
    }
}

__global__ __launch_bounds__(512, 2) void ctm_coop(CArgs a) {
  __shared__ __align__(16) char smem[34816];  // 17408 per half
  const int tid = threadIdx.x;                // 0..511
  const int half = tid >> 8;                  // 0/1
  const int htid = tid & 255;
  const int gbx = blockIdx.x;
  const int hid = gbx * 2 + half;             // half id 0..511
  char* hsm = smem + half * 17408;
  short* lsA = (short*)hsm;
  short* lsB = (short*)(hsm + 8192);
  float* hf = (float*)hsm;   // per-half float view
  float* sf = (float*)smem;  // whole-block float view
  int bi = 0;

  for (int t = 0; t < TICKS; ++t) {
    // ---- P1: qh GEMM (16 half-tasks) ; pack act -> pre[:,1024:] (rest) ----
    for (int u = hid; u < 16; u += NHALF)
      mm_tile64(a.syncA, NSYNC, a.Wt_qaq, NSYNC, u * 64, 0, NSYNC, htid, lsA, lsB,
                [&](int m, int n, float v) { a.qhb[m * DIN + n] = v + a.b_qaq[n]; });
    if (hid >= 16) {
      int stride = (NHALF - 16) * 256;
      for (int i = (hid - 16) * 256 + htid; i < B_ * DMODEL; i += stride) {
        int b = i >> 11, j = i & (DMODEL - 1);
        a.pre[(size_t)b * 3072 + DIN + j] = __float2bfloat16(a.act[i]);
      }
    }
    gbar(a.bar, bi++);
    // ---- P2: attention (1024 tasks, 2 per half) ----
    for (int u = hid; u < B_ * NH; u += NHALF) {
      const int b = u >> 4, h = u & (NH - 1);
      const __hip_bfloat16* Kp = a.kh + (size_t)u * (S_ * DH);
      const __hip_bfloat16* Vp = a.vh + (size_t)u * (S_ * DH);
      float* qs = hf;           // 64 f
      float* wv = hf + 64;      // 512 f
      float* red = hf + 576;    // 256 f
      float* red2 = hf + 1024;  // 2048 f
      if (htid < DH) qs[htid] = a.qhb[b * DIN + h * DH + htid];
      __syncthreads();
      float sc[2];
#pragma unroll
      for (int r = 0; r < 2; ++r) {
        int s = htid + r * 256;
        const short8* kp = reinterpret_cast<const short8*>(Kp + (size_t)s * DH);
        float accv = 0.f;
#pragma unroll
        for (int q = 0; q < 8; ++q) {
          short8 kk = kp[q];
#pragma unroll
          for (int j = 0; j < 8; ++j) accv += qs[q * 8 + j] * bfs(kk[j]);
        }
        sc[r] = accv * 0.125f;
      }
      red[htid] = fmaxf(sc[0], sc[1]);
      __syncthreads();
      for (int st = 128; st > 0; st >>= 1) {
        if (htid < st) red[htid] = fmaxf(red[htid], red[htid + st]);
        __syncthreads();
      }
      const float mx = red[0];
      __syncthreads();
      float e0 = expf(sc[0] - mx), e1 = expf(sc[1] - mx);
      wv[htid] = e0;
      wv[htid + 256] = e1;
      red[htid] = e0 + e1;
      __syncthreads();
      for (int st = 128; st > 0; st >>= 1) {
        if (htid < st) red[htid] += red[htid + st];
        __syncthreads();
      }
      const float invZ = 1.f / red[0];
      __syncthreads();
      const int d8 = htid & 7, sg = htid >> 3;
      float pacc[8];
#pragma unroll
      for (int j = 0; j < 8; ++j) pacc[j] = 0.f;
      for (int s = sg; s < S_; s += 32) {
        float wgt = wv[s];
        short8 vv = *reinterpret_cast<const short8*>(Vp + (size_t)s * DH + d8 * 8);
#pragma unroll
        for (int j = 0; j < 8; ++j) pacc[j] += wgt * bfs(vv[j]);
      }
#pragma unroll
      for (int j = 0; j < 8; ++j) red2[sg * 64 + d8 * 8 + j] = pacc[j];
      __syncthreads();
      if (htid < DH) {
        float r = 0.f;
#pragma unroll
        for (int g2 = 0; g2 < 32; ++g2) r += red2[g2 * 64 + htid];
        a.attnv[b * DIN + h * DH + htid] = __float2bfloat16(r * invZ);
      }
      __syncthreads();
    }
    gbar(a.bar, bi++);
    // ---- P3: ao GEMM -> pre[:, :1024] (16 half-tasks) ----
    for (int u = hid; u < 16; u += NHALF)
      mm_tile64(a.attnv, DIN, a.Wt_ao, DIN, u * 64, 0, DIN, htid, lsA, lsB,
                [&](int m, int n, float v) {
                  a.pre[(size_t)m * 3072 + n] = __float2bfloat16(v + a.b_ao[n]);
                });
    gbar(a.bar, bi++);
    // ---- P4: s1 GEMM split-K16 (512 half-tasks, chunk 192) ----
    for (int u = hid; u < 512; u += NHALF) {
      int nt = u & 31, ks = u >> 5;
      mm_tile64(a.pre, 3072, a.Wt_s1, 3072, nt * 64, ks * 192, 192, htid, lsA, lsB,
                [&](int m, int n, float v) { a.part[((size_t)ks * 64 + m) * DMODEL + n] = v; });
    }
    gbar(a.bar, bi++);
    // ---- P5: s1 reduce + gelu -> h1 (512 half-tasks) ----
    for (int u = hid; u < 512; u += NHALF) {
      int row = u >> 3, chunk = u & 7;
      int n = chunk * 256 + htid;
      float s = a.b_s1[n];
      for (int ks = 0; ks < 16; ks++) s += a.part[((size_t)ks * 64 + row) * DMODEL + n];
      a.h1[(size_t)row * DMODEL + n] = __float2bfloat16(gelu_f(s));
    }
    gbar(a.bar, bi++);
    // ---- P6: s2 GEMM split-K16 (512 half-tasks, chunk 128) ----
    for (int u = hid; u < 512; u += NHALF) {
      int nt = u & 31, ks = u >> 5;
      mm_tile64(a.h1, DMODEL, a.Wt_s2, DMODEL, nt * 64, ks * 128, 128, htid, lsA, lsB,
                [&](int m, int n, float v) { a.part[((size_t)ks * 64 + m) * DMODEL + n] = v; });
    }
    gbar(a.bar, bi++);
    // ---- P7: s2 reduce + LN -> hist slot 32+t (64 block-tasks, 512 thr) ----
    for (int u = gbx; u < 64; u += GPERS) {
      float v4[4];
      float s = 0.f, s2 = 0.f;
#pragma unroll
      for (int i = 0; i < 4; i++) {
        int n = tid + i * 512;
        float x = a.b_s2[n];
        for (int ks = 0; ks < 16; ks++) x += a.part[((size_t)ks * 64 + u) * DMODEL + n];
        v4[i] = x;
        s += x;
        s2 += x * x;
      }
      float* r1 = sf;
      float* r2 = sf + 512;
      r1[tid] = s;
      r2[tid] = s2;
      __syncthreads();
      for (int st = 256; st > 0; st >>= 1) {
        if (tid < st) {
          r1[tid] += r1[tid + st];
          r2[tid] += r2[tid + st];
        }
        __syncthreads();
      }
      float mean = r1[0] / DMODEL;
      float var = r2[0] / DMODEL - mean * mean;
      float inv = 1.f / sqrtf(var + 1e-5f);
      __syncthreads();
#pragma unroll
      for (int i = 0; i < 4; i++) {
        int n = tid + i * 512;
        float pa = (v4[i] - mean) * inv * a.g_s[n] + a.be_s[n];
        a.histf[((size_t)u * DMODEL + n) * HIST_W + 32 + t] = pa;
      }
      __syncthreads();
    }
    gbar(a.bar, bi++);
    // ---- P8: NLM (512 half-tasks) ----
    for (int u = hid; u < 512; u += NHALF) {
      float* w1s = hf;         // 4096 f
      float* b1s = hf + 4096;  // 128 f
      int d0 = u * 4;
      for (int i = htid; i < 4096; i += 256) w1s[i] = a.W_n1[(size_t)d0 * 1024 + i];
      if (htid < 128) b1s[htid] = a.b_n1[d0 * 32 + htid];
      __syncthreads();
      int b = htid & 63, dsub = htid >> 6;
      int d = d0 + dsub;
      const float* hw = a.histf + ((size_t)(b * DMODEL + d)) * HIST_W + t + 1;
      float win[DMEM];
#pragma unroll
      for (int m = 0; m < DMEM; ++m) win[m] = hw[m];
      const float* w1 = w1s + dsub * 1024;
      const float* bb = b1s + dsub * 32;
      const float* w2 = a.W_n2 + d * HNLM;
      float acc = 0.f;
      for (int h = 0; h < HNLM; ++h) {
        float s = bb[h];
#pragma unroll
        for (int m = 0; m < DMEM; ++m) s += win[m] * w1[m * HNLM + h];
        acc += fmaxf(s, 0.f) * w2[h];
      }
      a.nlmraw[(size_t)b * DMODEL + d] = acc + a.b_n2[d];
      __syncthreads();
    }
    gbar(a.bar, bi++);
    // ---- P9: LN(nlmraw)->act ; syncA(t+1), syncO(t) (64 block-tasks) ----
    for (int u = gbx; u < 64; u += GPERS) {
      const float* xr = a.nlmraw + (size_t)u * DMODEL;
      float* arow = sf;        // 2048 f
      float* r1 = sf + 2048;   // 512 f
      float* r2 = sf + 2560;   // 512 f
      float xv[4];
      float s = 0.f, s2 = 0.f;
#pragma unroll
      for (int i = 0; i < 4; i++) {
        float x = xr[tid + i * 512];
        xv[i] = x;
        s += x;
        s2 += x * x;
      }
      r1[tid] = s;
      r2[tid] = s2;
      __syncthreads();
      for (int st = 256; st > 0; st >>= 1) {
        if (tid < st) {
          r1[tid] += r1[tid + st];
          r2[tid] += r2[tid + st];
        }
        __syncthreads();
      }
      float mean = r1[0] / DMODEL;
      float var = r2[0] / DMODEL - mean * mean;
      float inv = 1.f / sqrtf(var + 1e-5f);
      __syncthreads();
#pragma unroll
      for (int i = 0; i < 4; i++) {
        int n = tid + i * 512;
        float av = (xv[i] - mean) * inv * a.g_n[n] + a.be_n[n];
        a.act[(size_t)u * DMODEL + n] = av;
        arow[n] = av;
      }
      __syncthreads();
      for (int j = tid; j < NSYNC; j += 512) {
        size_t idx = (size_t)u * NSYNC + j;
        float pA = arow[a.la[j]] * arow[a.ra[j]];
        float r = a.rAv[j];
        float av2 = r * a.aA[idx] + pA, bv2 = r * a.bA[idx] + 1.f;
        a.aA[idx] = av2;
        a.bA[idx] = bv2;
        a.syncA[idx] = __float2bfloat16(av2 / sqrtf(bv2));
        float pO = arow[a.lo[j]] * arow[a.ro[j]];
        float ro = a.rOv[j];
        av2 = ro * a.aO[idx] + pO;
        bv2 = ro * a.bO[idx] + 1.f;
        a.aO[idx] = av2;
        a.bO[idx] = bv2;
        a.syncO[idx] = __float2bfloat16(av2 / sqrtf(bv2));
      }
      __syncthreads();
    }
    // (no barrier: P10 task u consumes syncO row u written by the SAME block)
    // ---- P10: output head (64 block-tasks, 512 thr) ----
    for (int u = gbx; u < 64; u += GPERS) {
      float* so = sf;          // 512 f
      float* pv = sf + 512;    // 1024 f
      float* red = sf + 1536;  // 512 f
      so[tid] = __bfloat162float(a.syncO[(size_t)u * NSYNC + tid]);
      __syncthreads();
      float pr[2];
#pragma unroll
      for (int i = 0; i < 2; i++) {
        int n = tid + i * 512;
        pr[i] = 0.f;
        if (n < DOUT) {
          const unsigned* wr = reinterpret_cast<const unsigned*>(a.Wt_out + (size_t)n * NSYNC);
          float sacc = a.b_out[n];
          for (int c = 0; c < 256; c++) {
            unsigned uu = wr[c];
            sacc += so[2 * c] * bf_lo(uu) + so[2 * c + 1] * bf_hi(uu);
          }
          pr[i] = sacc;
          pv[n] = sacc;
        }
      }
      __syncthreads();
      float m = -1e30f;
      for (int o = tid; o < DOUT; o += 512) m = fmaxf(m, pv[o]);
      red[tid] = m;
      __syncthreads();
      for (int st = 256; st > 0; st >>= 1) {
        if (tid < st) red[tid] = fmaxf(red[tid], red[tid + st]);
        __syncthreads();
      }
      m = red[0];
      __syncthreads();
      float z = 0.f, s1 = 0.f;
      for (int o = tid; o < DOUT; o += 512) {
        float wv2 = pv[o] - m;
        float e = expf(wv2);
        z += e;
        s1 += e * wv2;
      }
      red[tid] = z;
      __syncthreads();
      for (int st = 256; st > 0; st >>= 1) {
        if (tid < st) red[tid] += red[tid + st];
        __syncthreads();
      }
      const float Z = red[0];
      __syncthreads();
      red[tid] = s1;
      __syncthreads();
      for (int st = 256; st > 0; st >>= 1) {
        if (tid < st) red[tid] += red[tid + st];
        __syncthreads();
      }
      const float S1 = red[0];
      const float ne = -(S1 / Z - logf(Z)) / 6.907755278982137f;
#pragma unroll
      for (int i = 0; i < 2; i++) {
        int n = tid + i * 512;
        if (n < DOUT) a.outp[((size_t)u * DOUT + n) * TICKS + t] = pr[i];
      }
      if (tid == 0) {
        float* c = a.outp + (size_t)B_ * DOUT * TICKS;
        c[u * 2 * TICKS + t] = ne;
        c[u * 2 * TICKS + TICKS + t] = 1.f - ne;
      }
      __syncthreads();
    }
    gbar(a.bar, bi++);
  }
}

// ---------------------------------------------------------------------------
extern "C" void kernel_launch(void* const* d_in, const int* in_sizes, int n_in,
                              void* d_out, int out_size, void* d_ws, size_t ws_size,
                              hipStream_t stream) {
  const float* x = (const float*)d_in[0];
  const float* W_kv = (const float*)d_in[1];
  const float* b_kv = (const float*)d_in[2];
  const float* g_kv = (const float*)d_in[3];
  const float* be_kv = (const float*)d_in[4];
  const float* W_q = (const float*)d_in[5];
  const float* b_q = (const float*)d_in[6];
  const float* W_aq = (const float*)d_in[7];
  const float* b_aq = (const float*)d_in[8];
  const float* W_ak = (const float*)d_in[9];
  const float* b_ak = (const float*)d_in[10];
  const float* W_av = (const float*)d_in[11];
  const float* b_av = (const float*)d_in[12];
  const float* W_ao = (const float*)d_in[13];
  const float* b_ao = (const float*)d_in[14];
  const float* W_s1 = (const float*)d_in[15];
  const float* b_s1 = (const float*)d_in[16];
  const float* W_s2 = (const float*)d_in[17];
  const float* b_s2 = (const float*)d_in[18];
  const float* g_s = (const float*)d_in[19];
  const float* be_s = (const float*)d_in[20];
  const float* W_n1 = (const float*)d_in[21];
  const float* b_n1 = (const float*)d_in[22];
  const float* W_n2 = (const float*)d_in[23];
  const float* b_n2 = (const float*)d_in[24];
  const float* g_n = (const float*)d_in[25];
  const float* be_n = (const float*)d_in[26];
  const float* init_state = (const float*)d_in[27];
  const float* init_hist = (const float*)d_in[28];
  const float* decay_action = (const float*)d_in[29];
  const float* decay_out = (const float*)d_in[30];
  const float* W_out = (const float*)d_in[31];
  const float* b_out = (const float*)d_in[32];
  const int* idx_la = (const int*)d_in[33];
  const int* idx_ra = (const int*)d_in[34];
  const int* idx_lo = (const int*)d_in[35];
  const int* idx_ro = (const int*)d_in[36];
  float* out = (float*)d_out;

  // ---- workspace carve ----
  char* wsb = (char*)d_ws;
  size_t off = 0;
  auto alloc = [&](size_t bytes) -> char* {
    char* p = wsb + off;
    off += (bytes + 255) & ~(size_t)255;
    return p;
  };
  const size_t MS = (size_t)B_ * S_;  // 32768
  char* regionA = alloc(MS * DIN * 4);  // kvraw fp32; later kh+vh bf16 (head-major)
  __hip_bfloat16* kv = (__hip_bfloat16*)alloc(MS * DIN * 2);
  float* histf = (float*)alloc((size_t)B_ * DMODEL * HIST_W * 4);
  __hip_bfloat16* Wt_kv = (__hip_bfloat16*)alloc((size_t)DIN * F_ * 2);
  __hip_bfloat16* Wt_ak = (__hip_bfloat16*)alloc((size_t)DIN * DIN * 2);
  __hip_bfloat16* Wt_av = (__hip_bfloat16*)alloc((size_t)DIN * DIN * 2);
  __hip_bfloat16* Wt_aq = (__hip_bfloat16*)alloc((size_t)DIN * DIN * 2);
  __hip_bfloat16* Wt_ao = (__hip_bfloat16*)alloc((size_t)DIN * DIN * 2);
  __hip_bfloat16* W_qb = (__hip_bfloat16*)alloc((size_t)NSYNC * DIN * 2);
  __hip_bfloat16* Wt_qaq = (__hip_bfloat16*)alloc((size_t)DIN * NSYNC * 2);
  __hip_bfloat16* Wt_s1 = (__hip_bfloat16*)alloc((size_t)DMODEL * (DIN + DMODEL) * 2);
  __hip_bfloat16* Wt_s2 = (__hip_bfloat16*)alloc((size_t)DMODEL * DMODEL * 2);
  __hip_bfloat16* Wt_out = (__hip_bfloat16*)alloc((size_t)DOUT * NSYNC * 2);
  float* b_qaq = (float*)alloc(DIN * 4);
  float* partial = (float*)alloc((size_t)16 * 64 * DMODEL * 4);  // split-K 16
  float* act = (float*)alloc((size_t)B_ * DMODEL * 4);
  float* aA = (float*)alloc((size_t)B_ * NSYNC * 4);
  float* bA = (float*)alloc((size_t)B_ * NSYNC * 4);
  float* aO = (float*)alloc((size_t)B_ * NSYNC * 4);
  float* bO = (float*)alloc((size_t)B_ * NSYNC * 4);
  __hip_bfloat16* syncA = (__hip_bfloat16*)alloc((size_t)B_ * NSYNC * 2);
  __hip_bfloat16* syncO = (__hip_bfloat16*)alloc((size_t)B_ * NSYNC * 2);
  float* qhb = (float*)alloc((size_t)B_ * DIN * 4);
  __hip_bfloat16* attnv = (__hip_bfloat16*)alloc((size_t)B_ * DIN * 2);
  __hip_bfloat16* pre = (__hip_bfloat16*)alloc((size_t)B_ * (DIN + DMODEL) * 2);
  __hip_bfloat16* h1 = (__hip_bfloat16*)alloc((size_t)B_ * DMODEL * 2);
  float* nlmraw = (float*)alloc((size_t)B_ * DMODEL * 4);
  float* rAv = (float*)alloc(NSYNC * 4);
  float* rOv = (float*)alloc(NSYNC * 4);
  char* gbarrier = alloc((size_t)BAR_SLOTS * BAR_STRIDE);  // 160 two-level slots

  float* kvraw = (float*)regionA;
  __hip_bfloat16* kh = (__hip_bfloat16*)regionA;                   // [b][h][s][d]
  __hip_bfloat16* vh = (__hip_bfloat16*)(regionA + MS * DIN * 2);  // [b][h][s][d]

  hipMemsetAsync(gbarrier, 0, (size_t)BAR_SLOTS * BAR_STRIDE, stream);

  dim3 t32x8(32, 8);
  // ---- weight prep ----
  transpose_bf16_kernel<<<dim3(F_ / 32, DIN / 32), t32x8, 0, stream>>>(W_kv, Wt_kv, F_, DIN, DIN);
  transpose_bf16_kernel<<<dim3(DIN / 32, DIN / 32), t32x8, 0, stream>>>(W_ak, Wt_ak, DIN, DIN, DIN);
  transpose_bf16_kernel<<<dim3(DIN / 32, DIN / 32), t32x8, 0, stream>>>(W_av, Wt_av, DIN, DIN, DIN);
  transpose_bf16_kernel<<<dim3(DIN / 32, DIN / 32), t32x8, 0, stream>>>(W_aq, Wt_aq, DIN, DIN, DIN);
  transpose_bf16_kernel<<<dim3(DIN / 32, DIN / 32), t32x8, 0, stream>>>(W_ao, Wt_ao, DIN, DIN, DIN);
  transpose_bf16_kernel<<<dim3(DMODEL / 32, (DIN + DMODEL) / 32), t32x8, 0, stream>>>(
      W_s1, Wt_s1, DIN + DMODEL, DMODEL, DMODEL);
  transpose_bf16_kernel<<<dim3(DMODEL / 32, DMODEL / 32), t32x8, 0, stream>>>(W_s2, Wt_s2, DMODEL,
                                                                              DMODEL, DMODEL);
  transpose_bf16_kernel<<<dim3((DOUT + 31) / 32, NSYNC / 32), t32x8, 0, stream>>>(
      W_out, Wt_out, NSYNC, DOUT, DOUT);
  conv_bf16_kernel<<<(NSYNC * DIN + 255) / 256, 256, 0, stream>>>(W_q, W_qb, NSYNC * DIN);
  bqaq_kernel<<<4, 256, 0, stream>>>(b_q, b_aq, Wt_aq, b_qaq);

  // ---- precompute ----
  gemm_big<0, float, float><<<dim3(DIN / 128, MS / 128), 256, 0, stream>>>(x, Wt_kv, b_kv, kvraw,
                                                                           (int)MS, DIN, F_);
  ln_kernel<__hip_bfloat16><<<(int)MS, 256, 0, stream>>>(kvraw, g_kv, be_kv, kv, DIN, DIN, 1);
  gemm_big<2, __hip_bfloat16, __hip_bfloat16><<<dim3(DIN / 128, MS / 128), 256, 0, stream>>>(
      kv, Wt_ak, b_ak, kh, (int)MS, DIN, DIN);
  gemm_big<2, __hip_bfloat16, __hip_bfloat16><<<dim3(DIN / 128, MS / 128), 256, 0, stream>>>(
      kv, Wt_av, b_av, vh, (int)MS, DIN, DIN);
  gemm_big<1, __hip_bfloat16, __hip_bfloat16><<<dim3(DIN / 128, NSYNC / 128), 256, 0, stream>>>(
      W_qb, Wt_aq, nullptr, Wt_qaq, NSYNC, DIN, DIN);

  // ---- state init ----
  init_act_kernel<<<(B_ * DMODEL + 255) / 256, 256, 0, stream>>>(init_state, act);
  init_hist_kernel<<<(B_ * DMODEL * DMEM + 255) / 256, 256, 0, stream>>>(init_hist, histf);
  init_sync_kernel<<<(B_ * NSYNC + 255) / 256, 256, 0, stream>>>(
      init_state, decay_action, decay_out, idx_la, idx_ra, idx_lo, idx_ro, aA, bA, aO, bO, syncA,
      rAv, rOv);

  // ---- persistent tick loop (256 blocks x 512 threads) ----
  CArgs ca;
  ca.Wt_qaq = Wt_qaq; ca.Wt_ao = Wt_ao; ca.Wt_s1 = Wt_s1; ca.Wt_s2 = Wt_s2; ca.Wt_out = Wt_out;
  ca.kh = kh; ca.vh = vh;
  ca.b_qaq = b_qaq; ca.b_ao = b_ao; ca.b_s1 = b_s1; ca.b_s2 = b_s2; ca.b_out = b_out;
  ca.g_s = g_s; ca.be_s = be_s; ca.g_n = g_n; ca.be_n = be_n;
  ca.W_n1 = W_n1; ca.b_n1 = b_n1; ca.W_n2 = W_n2; ca.b_n2 = b_n2;
  ca.la = idx_la; ca.ra = idx_ra; ca.lo = idx_lo; ca.ro = idx_ro;
  ca.rAv = rAv; ca.rOv = rOv;
  ca.qhb = qhb; ca.part = partial; ca.histf = histf; ca.act = act;
  ca.aA = aA; ca.bA = bA; ca.aO = aO; ca.bO = bO;
  ca.nlmraw = nlmraw; ca.outp = out;
  ca.syncA = syncA; ca.syncO = syncO; ca.attnv = attnv; ca.pre = pre; ca.h1 = h1;
  ca.bar = gbarrier;

  ctm_coop<<<GPERS, 512, 0, stream>>>(ca);

  (void)in_sizes; (void)n_in; (void)out_size; (void)ws_size;
}